// Round 1
// 171.152 us; speedup vs baseline: 1.0830x; 1.0830x over previous
//
#include <hip/hip_runtime.h>

#define NN 100000
#define NE 2400000
#define NB 391              // buckets of 256 dst nodes
#define CAP 6912            // per-bucket edge capacity (mean 6144, +9.8 sigma)
#define EPB 4096            // edges per sort block
#define NBLK2 ((NE + EPB - 1) / EPB)   // 586

__device__ __forceinline__ int wexscan(int v, int lane) {
    int x = v;
#pragma unroll
    for (int off = 1; off < 64; off <<= 1) {
        int t = __shfl_up(x, off, 64);
        x += (lane >= off) ? t : 0;
    }
    return x - v;            // exclusive prefix within wave64
}

// ---------------- pass 1: per-block bucket histogram (no global atomics) ----------------
__global__ __launch_bounds__(512) void k_hist(const int* __restrict__ ei,
        int* __restrict__ bh) {
    __shared__ int hist[NB];
    int tid = threadIdx.x;
    for (int i = tid; i < NB; i += 512) hist[i] = 0;
    __syncthreads();
    int base_e = blockIdx.x * EPB + tid * 8;
    if (base_e + 8 <= NE) {                  // NE%8==0: all-or-nothing per thread
        int4 da = *(const int4*)(ei + NE + base_e);
        int4 db = *(const int4*)(ei + NE + base_e + 4);
        atomicAdd(&hist[da.x >> 8], 1); atomicAdd(&hist[da.y >> 8], 1);
        atomicAdd(&hist[da.z >> 8], 1); atomicAdd(&hist[da.w >> 8], 1);
        atomicAdd(&hist[db.x >> 8], 1); atomicAdd(&hist[db.y >> 8], 1);
        atomicAdd(&hist[db.z >> 8], 1); atomicAdd(&hist[db.w >> 8], 1);
    }
    __syncthreads();
    for (int i = tid; i < NB; i += 512) bh[blockIdx.x * NB + i] = hist[i];
}

// ---------------- pass 2: per-bucket scan over blocks -> exact offsets ----------------
__global__ __launch_bounds__(256) void k_offscan(int* __restrict__ bh,
        int* __restrict__ tot) {
    __shared__ int wsum[4];
    int b = blockIdx.x, tid = threadIdx.x;
    int lane = tid & 63, wid = tid >> 6;
    int carry = 0;
#pragma unroll
    for (int r = 0; r < 3; ++r) {            // ceil(586/256)=3 rounds
        int blk = r * 256 + tid;
        int v = (blk < NBLK2) ? bh[blk * NB + b] : 0;
        int ex = wexscan(v, lane);
        if (lane == 63) wsum[wid] = ex + v;
        __syncthreads();
        int woff = 0, rt = 0;
#pragma unroll
        for (int i = 0; i < 4; ++i) {
            woff += (i < wid) ? wsum[i] : 0;
            rt += wsum[i];
        }
        if (blk < NBLK2) bh[blk * NB + b] = b * CAP + carry + woff + ex;
        carry += rt;
        __syncthreads();
    }
    if (tid == 0) tot[b] = carry;
}

// ---------------- pass 3: scatter to bucket regions (no global atomics) ----------------
__global__ __launch_bounds__(512) void k_scatter2(const int* __restrict__ ei,
        const int* __restrict__ bh, int* __restrict__ binned) {
    __shared__ int hist[NB], lbase[NB], myb[NB];
    __shared__ int stage[EPB];
    __shared__ unsigned short stageb[EPB];
    __shared__ int wsum[8];
    int tid = threadIdx.x;
    for (int i = tid; i < NB; i += 512) {
        hist[i] = 0;
        myb[i] = bh[blockIdx.x * NB + i];    // precomputed exact base
    }
    __syncthreads();
    int base_e = blockIdx.x * EPB + tid * 8;
    int pk[8], bn[8], rk[8];
    if (base_e + 8 <= NE) {
        const int4* s4 = (const int4*)(ei + base_e);
        const int4* d4 = (const int4*)(ei + NE + base_e);
        int4 sa = s4[0], sb = s4[1], da = d4[0], db = d4[1];
        int ss[8] = {sa.x, sa.y, sa.z, sa.w, sb.x, sb.y, sb.z, sb.w};
        int dd[8] = {da.x, da.y, da.z, da.w, db.x, db.y, db.z, db.w};
#pragma unroll
        for (int k = 0; k < 8; ++k) {
            bn[k] = dd[k] >> 8;
            pk[k] = ss[k] | ((dd[k] & 255) << 17);
            rk[k] = atomicAdd(&hist[bn[k]], 1);      // LDS rank only
        }
    } else {
#pragma unroll
        for (int k = 0; k < 8; ++k) bn[k] = -1;
    }
    __syncthreads();
    int lane = tid & 63, wid = tid >> 6;
    int v = (tid < NB) ? hist[tid] : 0;
    int ex = wexscan(v, lane);
    if (lane == 63) wsum[wid] = ex + v;
    __syncthreads();
    int woff = 0, tot = 0;
#pragma unroll
    for (int i = 0; i < 8; ++i) {
        int s = wsum[i];
        woff += (i < wid) ? s : 0;
        tot += s;
    }
    ex += woff;
    if (tid < NB) lbase[tid] = ex;
    __syncthreads();
#pragma unroll
    for (int k = 0; k < 8; ++k) {
        if (bn[k] >= 0) {
            int slot = lbase[bn[k]] + rk[k];
            stage[slot] = pk[k];
            stageb[slot] = (unsigned short)bn[k];
        }
    }
    __syncthreads();
    for (int j = tid; j < tot; j += 512) {
        int b = stageb[j];
        binned[myb[b] + (j - lbase[b])] = stage[j];
    }
}

// ---------------- per-bucket degree count -> rsp, dinv, prescaled xs ----------------
__global__ __launch_bounds__(256) void k_csr_count(const int* __restrict__ binned,
        const int* __restrict__ tot, const float* __restrict__ x,
        int* __restrict__ rsp, float* __restrict__ dinv, float2* __restrict__ xs) {
    __shared__ int cnt[256];
    __shared__ int wsum[4];
    int tid = threadIdx.x, b = blockIdx.x;
    int base = b * CAP, n = tot[b];
    cnt[tid] = 0;
    __syncthreads();
    int n4 = n >> 2;
    const int4* b4 = (const int4*)(binned + base);
    for (int j = tid; j < n4; j += 256) {
        int4 w = b4[j];
        atomicAdd(&cnt[(w.x >> 17) & 255], 1);
        atomicAdd(&cnt[(w.y >> 17) & 255], 1);
        atomicAdd(&cnt[(w.z >> 17) & 255], 1);
        atomicAdd(&cnt[(w.w >> 17) & 255], 1);
    }
    for (int j = (n4 << 2) + tid; j < n; j += 256)
        atomicAdd(&cnt[(binned[base + j] >> 17) & 255], 1);
    __syncthreads();
    int deg = cnt[tid];
    int lane = tid & 63, wid = tid >> 6;
    int ex = wexscan(deg, lane);
    if (lane == 63) wsum[wid] = ex + deg;
    __syncthreads();
    int woff = 0;
#pragma unroll
    for (int i = 0; i < 4; ++i) woff += (i < wid) ? wsum[i] : 0;
    ex += woff;
    int node = (b << 8) + tid;
    if (node < NN) {
        rsp[node] = ((base + ex) << 8) | deg;            // packed start|deg
        float di = rsqrtf((float)(deg + 1));             // +1 self-loop
        dinv[node] = di;
        float2 xv = ((const float2*)x)[node];
        xs[node] = make_float2(di * xv.x, di * xv.y);
    }
}

// ---------------- csr placement, then per-node register walk -> At ----------------
// xs fully written by k_csr_count (previous launch) -> safe to read any node here.
__global__ __launch_bounds__(256) void k_csr_place(const int* __restrict__ binned,
        const int* __restrict__ tot, const int* __restrict__ rsp,
        const float2* __restrict__ xs, const float* __restrict__ dinv,
        int* __restrict__ csr, float4* __restrict__ At) {
    __shared__ int cur2[256];
    int tid = threadIdx.x, b = blockIdx.x;
    int base = b * CAP, n = tot[b];
    int node = (b << 8) + tid;
    int rp = (node < NN) ? rsp[node] : 0;
    cur2[tid] = (node < NN) ? ((rp >> 8) - base) : 0;
    __syncthreads();
    int n4 = n >> 2;
    const int4* b4 = (const int4*)(binned + base);
    for (int j = tid; j < n4; j += 256) {
        int4 w = b4[j];
        int p0 = atomicAdd(&cur2[(w.x >> 17) & 255], 1); csr[base + p0] = w.x & 0x1FFFF;
        int p1 = atomicAdd(&cur2[(w.y >> 17) & 255], 1); csr[base + p1] = w.y & 0x1FFFF;
        int p2 = atomicAdd(&cur2[(w.z >> 17) & 255], 1); csr[base + p2] = w.z & 0x1FFFF;
        int p3 = atomicAdd(&cur2[(w.w >> 17) & 255], 1); csr[base + p3] = w.w & 0x1FFFF;
    }
    for (int j = (n4 << 2) + tid; j < n; j += 256) {
        int w = binned[base + j];
        int p = atomicAdd(&cur2[(w >> 17) & 255], 1);
        csr[base + p] = w & 0x1FFFF;
    }
    __syncthreads();                          // csr slice complete (in-block, L2-hot)
    if (node < NN) {
        int beg = rp >> 8, deg = rp & 255;
        float ax = 0.f, ay = 0.f;
        int e = beg, end = beg + deg;
        for (; e + 4 <= end; e += 4) {
            int s0 = csr[e], s1 = csr[e + 1], s2 = csr[e + 2], s3 = csr[e + 3];
            float2 v0 = xs[s0], v1 = xs[s1], v2 = xs[s2], v3 = xs[s3];
            ax += (v0.x + v1.x) + (v2.x + v3.x);
            ay += (v0.y + v1.y) + (v2.y + v3.y);
        }
        for (; e < end; ++e) { float2 vv = xs[csr[e]]; ax += vv.x; ay += vv.y; }
        float di = dinv[node];
        float2 xn = xs[node];                 // self-loop term
        At[node] = make_float4(di * (ax + xn.x), di * (ay + xn.y), di, 0.f);
    }
}

// ---------------- layer-2: octet gather (8 lanes/node, 4 features/lane) ----------------
// Replaces k_gather_fly. No LDS neighbor broadcast: all 8 lanes of an octet load the
// SAME At[s] float4 from global (1 line/octet, L2-resident). W2 column lives in 32 VGPRs
// per thread (f = tid&31 is invariant across tail rounds) -> no WsT LDS reads at all.
// LDS use collapses to one 32x36 accS transpose per node (broadcast b128 reads = free).
__global__ __launch_bounds__(256) void k_agg(const float4* __restrict__ At,
        const int* __restrict__ rsp, const int* __restrict__ csr,
        const float* __restrict__ W1, const float* __restrict__ b1,
        const float* __restrict__ W2, const float* __restrict__ b2,
        const float* __restrict__ W3, float* __restrict__ h3) {
    __shared__ float accS[32 * 36];           // [node_local][36] pad keeps b128 alignment
    __shared__ float diS[32];
    int tid = threadIdx.x;
    int o = tid & 7, nl = tid >> 3;           // octet lane, local node
    int node = blockIdx.x * 32 + nl;          // grid*32 == NN exactly
    int f = tid & 31;                         // tail feature (invariant across rounds)

    float4 w0 = *(const float4*)&W1[4 * o];        // W1 row 0, features 4o..4o+3
    float4 w1 = *(const float4*)&W1[32 + 4 * o];   // W1 row 1
    float4 bb = *(const float4*)&b1[4 * o];

    int r = rsp[node];
    int beg = r >> 8, deg = r & 255;
    float4 an = At[node];
    float di = an.z;

    float4 acc;
    {   // self-loop term: dinv[node]*relu(h1[node])
        float v0 = fmaf(an.y, w1.x, fmaf(an.x, w0.x, bb.x));
        float v1 = fmaf(an.y, w1.y, fmaf(an.x, w0.y, bb.y));
        float v2 = fmaf(an.y, w1.z, fmaf(an.x, w0.z, bb.z));
        float v3 = fmaf(an.y, w1.w, fmaf(an.x, w0.w, bb.w));
        acc.x = di * fmaxf(v0, 0.f);
        acc.y = di * fmaxf(v1, 0.f);
        acc.z = di * fmaxf(v2, 0.f);
        acc.w = di * fmaxf(v3, 0.f);
    }

    auto acc1 = [&](const float4& aa, float zz) {
        float v0 = fmaf(aa.y, w1.x, fmaf(aa.x, w0.x, bb.x));
        float v1 = fmaf(aa.y, w1.y, fmaf(aa.x, w0.y, bb.y));
        float v2 = fmaf(aa.y, w1.z, fmaf(aa.x, w0.z, bb.z));
        float v3 = fmaf(aa.y, w1.w, fmaf(aa.x, w0.w, bb.w));
        acc.x = fmaf(zz, fmaxf(v0, 0.f), acc.x);
        acc.y = fmaf(zz, fmaxf(v1, 0.f), acc.y);
        acc.z = fmaf(zz, fmaxf(v2, 0.f), acc.z);
        acc.w = fmaf(zz, fmaxf(v3, 0.f), acc.w);
    };

    for (int j = 0; j < deg; j += 4) {
        int e = beg + j;
        int t0 = csr[e];                       // j<deg: always valid
        int t1 = csr[e + 1], t2 = csr[e + 2], t3 = csr[e + 3];  // csr padded: safe reads
        int s1 = (j + 1 < deg) ? t1 : 0;       // clamp masked indices (value may be junk)
        int s2 = (j + 2 < deg) ? t2 : 0;
        int s3 = (j + 3 < deg) ? t3 : 0;
        float m1 = (j + 1 < deg) ? 1.f : 0.f;
        float m2 = (j + 2 < deg) ? 1.f : 0.f;
        float m3 = (j + 3 < deg) ? 1.f : 0.f;
        float4 a0 = At[t0], a1 = At[s1], a2 = At[s2], a3 = At[s3];
        float z0 = a0.z, z1 = m1 * a1.z, z2 = m2 * a2.z, z3 = m3 * a3.z;
        acc1(a0, z0); acc1(a1, z1); acc1(a2, z2); acc1(a3, z3);
    }

    // W2 column f into registers (issued before barrier, overlaps drain)
    float w2r[32];
#pragma unroll
    for (int k = 0; k < 32; ++k) w2r[k] = W2[k * 32 + f];

    acc.x *= di; acc.y *= di; acc.z *= di; acc.w *= di;   // agg2 quad
    *(float4*)&accS[nl * 36 + 4 * o] = acc;
    if (o == 0) diS[nl] = di;
    __syncthreads();

    float bf = b2[f], w3f = W3[f];
    int g = tid >> 5;                          // node-group for tail rounds
#pragma unroll
    for (int rr = 0; rr < 4; ++rr) {
        int n = g + 8 * rr;
        const float* arow = &accS[n * 36];
        float sum = bf;
#pragma unroll
        for (int k = 0; k < 32; k += 4) {
            float4 a4 = *(const float4*)&arow[k];    // 32-lane broadcast, free
            sum = fmaf(a4.x, w2r[k], sum);
            sum = fmaf(a4.y, w2r[k + 1], sum);
            sum = fmaf(a4.z, w2r[k + 2], sum);
            sum = fmaf(a4.w, w2r[k + 3], sum);
        }
        float h2 = fmaxf(sum, 0.f);
        float v = h2 * w3f;
#pragma unroll
        for (int off = 16; off > 0; off >>= 1) v += __shfl_down(v, off, 32);
        if (f == 0) h3[blockIdx.x * 32 + n] = diS[n] * v;
    }
}

// ---------------- width-1 gather -> out ----------------
__global__ __launch_bounds__(256) void k_gather_out(const float* __restrict__ hs,
        const int* __restrict__ rsp, const int* __restrict__ csr,
        const float* __restrict__ dinv, const float* __restrict__ bias,
        float* __restrict__ out) {
    int node = blockIdx.x * 256 + threadIdx.x;
    if (node >= NN) return;
    int r = rsp[node];
    int beg = r >> 8, end = beg + (r & 255);
    float acc = hs[node];
    int e = beg;
    for (; e + 4 <= end; e += 4) {
        int s0 = csr[e], s1 = csr[e + 1], s2 = csr[e + 2], s3 = csr[e + 3];
        acc += (hs[s0] + hs[s1]) + (hs[s2] + hs[s3]);
    }
    for (; e < end; ++e) acc += hs[csr[e]];
    out[node] = dinv[node] * acc + bias[0];
}

extern "C" void kernel_launch(void* const* d_in, const int* in_sizes, int n_in,
                              void* d_out, int out_size, void* d_ws, size_t ws_size,
                              hipStream_t stream) {
    const float* x  = (const float*)d_in[0];
    const int*   ei = (const int*)d_in[1];   // [2, NE] int32
    const float* W1 = (const float*)d_in[2];
    const float* b1 = (const float*)d_in[3];
    const float* W2 = (const float*)d_in[4];
    const float* b2 = (const float*)d_in[5];
    const float* W3 = (const float*)d_in[6];
    const float* b3 = (const float*)d_in[7];
    float* out = (float*)d_out;

    char* w = (char*)d_ws;
    float4* At    = (float4*)w; w += NN * 16;           // 16B-aligned first, 1.6 MB
    float2* xs    = (float2*)w; w += NN * 8;
    int*   bh     = (int*)w;    w += NBLK2 * NB * 4;    // 0.9 MB block-hist/offsets
    int*   tot    = (int*)w;    w += NB * 4;
    int*   rsp    = (int*)w;    w += NN * 4;
    float* dinv   = (float*)w;  w += NN * 4;
    int*   binned = (int*)w;    w += NB * CAP * 4;      // 10.8 MB
    int*   csr    = (int*)w;    w += (NB * CAP + 16) * 4; // 10.8 MB (+64B overread pad)
    float* h3     = (float*)w;  w += NN * 4;

    const int G_N = (NN + 255) / 256;        // 391
    const int G_A = NN / 32;                 // 3125 (exact)

    k_hist<<<NBLK2, 512, 0, stream>>>(ei, bh);
    k_offscan<<<NB, 256, 0, stream>>>(bh, tot);
    k_scatter2<<<NBLK2, 512, 0, stream>>>(ei, bh, binned);
    k_csr_count<<<NB, 256, 0, stream>>>(binned, tot, x, rsp, dinv, xs);
    k_csr_place<<<NB, 256, 0, stream>>>(binned, tot, rsp, xs, dinv, csr, At);
    k_agg<<<G_A, 256, 0, stream>>>(At, rsp, csr, W1, b1, W2, b2, W3, h3);
    k_gather_out<<<G_N, 256, 0, stream>>>(h3, rsp, csr, dinv, b3, out);
}

// Round 2
// 168.408 us; speedup vs baseline: 1.1006x; 1.0163x over previous
//
#include <hip/hip_runtime.h>

#define NN 100000
#define NE 2400000
#define NB 391              // buckets of 256 dst nodes
#define CAP 6912            // per-bucket edge capacity for binned (mean 6144, +9.8 sigma)
#define CAP2 7168           // per-bucket csr capacity incl. per-node pad-to-4 (mean 6528, +8 sigma)
#define EPB 4096            // edges per sort block
#define NBLK2 ((NE + EPB - 1) / EPB)   // 586
#define IMASK 0x1FFFF       // 17-bit index mask: bounds prefetch garbage into slack
#define SLACK 131072        // At/xs/h3 allocation (entries) so masked garbage reads stay in-bounds

__device__ __forceinline__ int wexscan(int v, int lane) {
    int x = v;
#pragma unroll
    for (int off = 1; off < 64; off <<= 1) {
        int t = __shfl_up(x, off, 64);
        x += (lane >= off) ? t : 0;
    }
    return x - v;            // exclusive prefix within wave64
}

// ---------------- pass 1: per-block bucket histogram (no global atomics) ----------------
__global__ __launch_bounds__(512) void k_hist(const int* __restrict__ ei,
        int* __restrict__ bh) {
    __shared__ int hist[NB];
    int tid = threadIdx.x;
    for (int i = tid; i < NB; i += 512) hist[i] = 0;
    __syncthreads();
    int base_e = blockIdx.x * EPB + tid * 8;
    if (base_e + 8 <= NE) {                  // NE%8==0: all-or-nothing per thread
        int4 da = *(const int4*)(ei + NE + base_e);
        int4 db = *(const int4*)(ei + NE + base_e + 4);
        atomicAdd(&hist[da.x >> 8], 1); atomicAdd(&hist[da.y >> 8], 1);
        atomicAdd(&hist[da.z >> 8], 1); atomicAdd(&hist[da.w >> 8], 1);
        atomicAdd(&hist[db.x >> 8], 1); atomicAdd(&hist[db.y >> 8], 1);
        atomicAdd(&hist[db.z >> 8], 1); atomicAdd(&hist[db.w >> 8], 1);
    }
    __syncthreads();
    for (int i = tid; i < NB; i += 512) bh[blockIdx.x * NB + i] = hist[i];
}

// ---------------- pass 2: per-bucket scan over blocks -> exact offsets ----------------
__global__ __launch_bounds__(256) void k_offscan(int* __restrict__ bh,
        int* __restrict__ tot) {
    __shared__ int wsum[4];
    int b = blockIdx.x, tid = threadIdx.x;
    int lane = tid & 63, wid = tid >> 6;
    int carry = 0;
#pragma unroll
    for (int r = 0; r < 3; ++r) {            // ceil(586/256)=3 rounds
        int blk = r * 256 + tid;
        int v = (blk < NBLK2) ? bh[blk * NB + b] : 0;
        int ex = wexscan(v, lane);
        if (lane == 63) wsum[wid] = ex + v;
        __syncthreads();
        int woff = 0, rt = 0;
#pragma unroll
        for (int i = 0; i < 4; ++i) {
            woff += (i < wid) ? wsum[i] : 0;
            rt += wsum[i];
        }
        if (blk < NBLK2) bh[blk * NB + b] = b * CAP + carry + woff + ex;
        carry += rt;
        __syncthreads();
    }
    if (tid == 0) tot[b] = carry;
}

// ---------------- pass 3: scatter to bucket regions (no global atomics) ----------------
__global__ __launch_bounds__(512) void k_scatter2(const int* __restrict__ ei,
        const int* __restrict__ bh, int* __restrict__ binned) {
    __shared__ int hist[NB], lbase[NB], myb[NB];
    __shared__ int stage[EPB];
    __shared__ unsigned short stageb[EPB];
    __shared__ int wsum[8];
    int tid = threadIdx.x;
    for (int i = tid; i < NB; i += 512) {
        hist[i] = 0;
        myb[i] = bh[blockIdx.x * NB + i];    // precomputed exact base
    }
    __syncthreads();
    int base_e = blockIdx.x * EPB + tid * 8;
    int pk[8], bn[8], rk[8];
    if (base_e + 8 <= NE) {
        const int4* s4 = (const int4*)(ei + base_e);
        const int4* d4 = (const int4*)(ei + NE + base_e);
        int4 sa = s4[0], sb = s4[1], da = d4[0], db = d4[1];
        int ss[8] = {sa.x, sa.y, sa.z, sa.w, sb.x, sb.y, sb.z, sb.w};
        int dd[8] = {da.x, da.y, da.z, da.w, db.x, db.y, db.z, db.w};
#pragma unroll
        for (int k = 0; k < 8; ++k) {
            bn[k] = dd[k] >> 8;
            pk[k] = ss[k] | ((dd[k] & 255) << 17);
            rk[k] = atomicAdd(&hist[bn[k]], 1);      // LDS rank only
        }
    } else {
#pragma unroll
        for (int k = 0; k < 8; ++k) bn[k] = -1;
    }
    __syncthreads();
    int lane = tid & 63, wid = tid >> 6;
    int v = (tid < NB) ? hist[tid] : 0;
    int ex = wexscan(v, lane);
    if (lane == 63) wsum[wid] = ex + v;
    __syncthreads();
    int woff = 0, tot = 0;
#pragma unroll
    for (int i = 0; i < 8; ++i) {
        int s = wsum[i];
        woff += (i < wid) ? s : 0;
        tot += s;
    }
    ex += woff;
    if (tid < NB) lbase[tid] = ex;
    __syncthreads();
#pragma unroll
    for (int k = 0; k < 8; ++k) {
        if (bn[k] >= 0) {
            int slot = lbase[bn[k]] + rk[k];
            stage[slot] = pk[k];
            stageb[slot] = (unsigned short)bn[k];
        }
    }
    __syncthreads();
    for (int j = tid; j < tot; j += 512) {
        int b = stageb[j];
        binned[myb[b] + (j - lbase[b])] = stage[j];
    }
}

// ---------------- per-bucket degree count -> rsp (padded csr offsets), dinv, xs --------
__global__ __launch_bounds__(256) void k_csr_count(const int* __restrict__ binned,
        const int* __restrict__ tot, const float* __restrict__ x,
        int* __restrict__ rsp, float* __restrict__ dinv, float2* __restrict__ xs) {
    __shared__ int cnt[256];
    __shared__ int wsum[4];
    int tid = threadIdx.x, b = blockIdx.x;
    int base = b * CAP, n = tot[b];
    cnt[tid] = 0;
    __syncthreads();
    int n4 = n >> 2;
    const int4* b4 = (const int4*)(binned + base);
    for (int j = tid; j < n4; j += 256) {
        int4 w = b4[j];
        atomicAdd(&cnt[(w.x >> 17) & 255], 1);
        atomicAdd(&cnt[(w.y >> 17) & 255], 1);
        atomicAdd(&cnt[(w.z >> 17) & 255], 1);
        atomicAdd(&cnt[(w.w >> 17) & 255], 1);
    }
    for (int j = (n4 << 2) + tid; j < n; j += 256)
        atomicAdd(&cnt[(binned[base + j] >> 17) & 255], 1);
    __syncthreads();
    int deg = cnt[tid];
    int degp = (deg + 3) & ~3;               // pad to multiple of 4 -> aligned int4 runs
    int lane = tid & 63, wid = tid >> 6;
    int ex = wexscan(degp, lane);
    if (lane == 63) wsum[wid] = ex + degp;
    __syncthreads();
    int woff = 0;
#pragma unroll
    for (int i = 0; i < 4; ++i) woff += (i < wid) ? wsum[i] : 0;
    ex += woff;
    int node = (b << 8) + tid;
    if (node < NN) {
        rsp[node] = ((b * CAP2 + ex) << 8) | deg;        // packed start|deg (csr-space)
        float di = rsqrtf((float)(deg + 1));             // +1 self-loop
        dinv[node] = di;
        float2 xv = ((const float2*)x)[node];
        xs[node] = make_float2(di * xv.x, di * xv.y);
    }
    if (node == NN) xs[NN] = make_float2(0.f, 0.f);      // sentinel for pad slots
}

// ---------------- csr placement (+pad sentinels), then pipelined per-node walk -> At ----
__global__ __launch_bounds__(256) void k_csr_place(const int* __restrict__ binned,
        const int* __restrict__ tot, const int* __restrict__ rsp,
        const float2* __restrict__ xs, const float* __restrict__ dinv,
        int* __restrict__ csr, float4* __restrict__ At) {
    __shared__ int cur2[256];
    int tid = threadIdx.x, b = blockIdx.x;
    int base = b * CAP, base2 = b * CAP2, n = tot[b];
    int node = (b << 8) + tid;
    int rp = (node < NN) ? rsp[node] : 0;
    cur2[tid] = (node < NN) ? ((rp >> 8) - base2) : 0;
    __syncthreads();
    int n4 = n >> 2;
    const int4* b4 = (const int4*)(binned + base);
    for (int j = tid; j < n4; j += 256) {
        int4 w = b4[j];
        int p0 = atomicAdd(&cur2[(w.x >> 17) & 255], 1); csr[base2 + p0] = w.x & IMASK;
        int p1 = atomicAdd(&cur2[(w.y >> 17) & 255], 1); csr[base2 + p1] = w.y & IMASK;
        int p2 = atomicAdd(&cur2[(w.z >> 17) & 255], 1); csr[base2 + p2] = w.z & IMASK;
        int p3 = atomicAdd(&cur2[(w.w >> 17) & 255], 1); csr[base2 + p3] = w.w & IMASK;
    }
    for (int j = (n4 << 2) + tid; j < n; j += 256) {
        int w = binned[base + j];
        int p = atomicAdd(&cur2[(w >> 17) & 255], 1);
        csr[base2 + p] = w & IMASK;
    }
    __syncthreads();                          // csr slice complete (in-block, L2-hot)
    if (node == NN) At[NN] = make_float4(0.f, 0.f, 0.f, 0.f);   // sentinel
    if (node < NN) {
        int beg = rp >> 8, deg = rp & 255;
        int degp = (deg + 3) & ~3, nIt = degp >> 2;
        for (int p = deg; p < degp; ++p) csr[beg + p] = NN;     // own-range pad fill
        float ax = 0.f, ay = 0.f;
        const int4* cp = (const int4*)(csr + beg);
        if (nIt > 0) {
            int4 c1 = cp[1];                  // overread: in-bucket slack / global pad
            int4 c0 = cp[0];
            float2 A0 = xs[c0.x & IMASK], A1 = xs[c0.y & IMASK];
            float2 A2 = xs[c0.z & IMASK], A3 = xs[c0.w & IMASK];
            for (int it = 0; it < nIt; ++it) {
                int4 cn = cp[it + 2];                           // 2-ahead index prefetch
                float2 B0 = xs[c1.x & IMASK], B1 = xs[c1.y & IMASK];
                float2 B2 = xs[c1.z & IMASK], B3 = xs[c1.w & IMASK];
                ax += (A0.x + A1.x) + (A2.x + A3.x);
                ay += (A0.y + A1.y) + (A2.y + A3.y);
                A0 = B0; A1 = B1; A2 = B2; A3 = B3;
                c1 = cn;
            }
        }
        float di = dinv[node];
        float2 xn = xs[node];                 // self-loop term
        At[node] = make_float4(di * (ax + xn.x), di * (ay + xn.y), di, 0.f);
    }
}

// ---------------- layer-2: octet gather (8 lanes/node, 4 features/lane), pipelined -----
// No LDS neighbor broadcast: 8 lanes of an octet load the SAME At[s] float4 (1 line/octet,
// L2-resident). csr runs are 4-padded -> one aligned int4 per quad. Indices prefetched
// 2-deep, At payload 1-deep: FMAs never wait on the loads issued in the same iteration.
// Pad slots hold sentinel NN with At[NN]=0 (z=0 -> contributes exactly 0); overread
// garbage is masked into the SLACK region and never accumulated.
__global__ __launch_bounds__(256) void k_agg(const float4* __restrict__ At,
        const int* __restrict__ rsp, const int* __restrict__ csr,
        const float* __restrict__ W1, const float* __restrict__ b1,
        const float* __restrict__ W2, const float* __restrict__ b2,
        const float* __restrict__ W3, float* __restrict__ h3) {
    __shared__ float accS[32 * 36];           // [node_local][36] pad keeps b128 alignment
    __shared__ float diS[32];
    int tid = threadIdx.x;
    if (blockIdx.x == 0 && tid == 0) h3[NN] = 0.f;   // sentinel for k_gather_out
    int o = tid & 7, nl = tid >> 3;           // octet lane, local node
    int node = blockIdx.x * 32 + nl;          // grid*32 == NN exactly
    int f = tid & 31;                         // tail feature (invariant across rounds)

    float4 w0 = *(const float4*)&W1[4 * o];        // W1 row 0, features 4o..4o+3
    float4 w1 = *(const float4*)&W1[32 + 4 * o];   // W1 row 1
    float4 bb = *(const float4*)&b1[4 * o];

    int r = rsp[node];
    int beg = r >> 8, deg = r & 255;
    int degp = (deg + 3) & ~3, nIt = degp >> 2;
    float4 an = At[node];
    float di = an.z;

    float4 acc;
    {   // self-loop term: dinv[node]*relu(h1[node])
        float v0 = fmaf(an.y, w1.x, fmaf(an.x, w0.x, bb.x));
        float v1 = fmaf(an.y, w1.y, fmaf(an.x, w0.y, bb.y));
        float v2 = fmaf(an.y, w1.z, fmaf(an.x, w0.z, bb.z));
        float v3 = fmaf(an.y, w1.w, fmaf(an.x, w0.w, bb.w));
        acc.x = di * fmaxf(v0, 0.f);
        acc.y = di * fmaxf(v1, 0.f);
        acc.z = di * fmaxf(v2, 0.f);
        acc.w = di * fmaxf(v3, 0.f);
    }

    auto acc1 = [&](const float4& aa) {       // zz = aa.z (0 for pad/sentinel)
        float v0 = fmaf(aa.y, w1.x, fmaf(aa.x, w0.x, bb.x));
        float v1 = fmaf(aa.y, w1.y, fmaf(aa.x, w0.y, bb.y));
        float v2 = fmaf(aa.y, w1.z, fmaf(aa.x, w0.z, bb.z));
        float v3 = fmaf(aa.y, w1.w, fmaf(aa.x, w0.w, bb.w));
        acc.x = fmaf(aa.z, fmaxf(v0, 0.f), acc.x);
        acc.y = fmaf(aa.z, fmaxf(v1, 0.f), acc.y);
        acc.z = fmaf(aa.z, fmaxf(v2, 0.f), acc.z);
        acc.w = fmaf(aa.z, fmaxf(v3, 0.f), acc.w);
    };

    const int4* cp = (const int4*)(csr + beg);     // octet-uniform, 16B-aligned
    {
        int4 c0 = cp[0], c1 = cp[1];               // overread-safe (bucket slack + pad)
        float4 A0 = At[c0.x & IMASK], A1 = At[c0.y & IMASK];
        float4 A2 = At[c0.z & IMASK], A3 = At[c0.w & IMASK];
        for (int it = 0; it < nIt; ++it) {
            int4 cn = cp[it + 2];                  // 2-ahead index prefetch
            float4 B0 = At[c1.x & IMASK], B1 = At[c1.y & IMASK];
            float4 B2 = At[c1.z & IMASK], B3 = At[c1.w & IMASK];
            acc1(A0); acc1(A1); acc1(A2); acc1(A3);
            A0 = B0; A1 = B1; A2 = B2; A3 = B3;
            c1 = cn;
        }
    }

    // W2 column f into registers (after edge loop -> low live range in hot loop)
    float w2r[32];
#pragma unroll
    for (int k = 0; k < 32; ++k) w2r[k] = W2[k * 32 + f];

    acc.x *= di; acc.y *= di; acc.z *= di; acc.w *= di;   // agg2 quad
    *(float4*)&accS[nl * 36 + 4 * o] = acc;
    if (o == 0) diS[nl] = di;
    __syncthreads();

    float bf = b2[f], w3f = W3[f];
    int g = tid >> 5;                          // node-group for tail rounds
#pragma unroll
    for (int rr = 0; rr < 4; ++rr) {
        int n = g + 8 * rr;
        const float* arow = &accS[n * 36];
        float sum = bf;
#pragma unroll
        for (int k = 0; k < 32; k += 4) {
            float4 a4 = *(const float4*)&arow[k];    // 32-lane broadcast, free
            sum = fmaf(a4.x, w2r[k], sum);
            sum = fmaf(a4.y, w2r[k + 1], sum);
            sum = fmaf(a4.z, w2r[k + 2], sum);
            sum = fmaf(a4.w, w2r[k + 3], sum);
        }
        float h2 = fmaxf(sum, 0.f);
        float v = h2 * w3f;
#pragma unroll
        for (int off = 16; off > 0; off >>= 1) v += __shfl_down(v, off, 32);
        if (f == 0) h3[blockIdx.x * 32 + n] = diS[n] * v;
    }
}

// ---------------- width-1 gather -> out (pipelined, padded int4) ----------------
__global__ __launch_bounds__(256) void k_gather_out(const float* __restrict__ hs,
        const int* __restrict__ rsp, const int* __restrict__ csr,
        const float* __restrict__ dinv, const float* __restrict__ bias,
        float* __restrict__ out) {
    int node = blockIdx.x * 256 + threadIdx.x;
    if (node >= NN) return;
    int r = rsp[node];
    int beg = r >> 8, deg = r & 255;
    int degp = (deg + 3) & ~3, nIt = degp >> 2;
    float acc = hs[node];
    const int4* cp = (const int4*)(csr + beg);
    if (nIt > 0) {
        int4 c0 = cp[0], c1 = cp[1];
        float A0 = hs[c0.x & IMASK], A1 = hs[c0.y & IMASK];
        float A2 = hs[c0.z & IMASK], A3 = hs[c0.w & IMASK];
        for (int it = 0; it < nIt; ++it) {
            int4 cn = cp[it + 2];
            float B0 = hs[c1.x & IMASK], B1 = hs[c1.y & IMASK];
            float B2 = hs[c1.z & IMASK], B3 = hs[c1.w & IMASK];
            acc += (A0 + A1) + (A2 + A3);
            A0 = B0; A1 = B1; A2 = B2; A3 = B3;
            c1 = cn;
        }
    }
    out[node] = dinv[node] * acc + bias[0];
}

extern "C" void kernel_launch(void* const* d_in, const int* in_sizes, int n_in,
                              void* d_out, int out_size, void* d_ws, size_t ws_size,
                              hipStream_t stream) {
    const float* x  = (const float*)d_in[0];
    const int*   ei = (const int*)d_in[1];   // [2, NE] int32
    const float* W1 = (const float*)d_in[2];
    const float* b1 = (const float*)d_in[3];
    const float* W2 = (const float*)d_in[4];
    const float* b2 = (const float*)d_in[5];
    const float* W3 = (const float*)d_in[6];
    const float* b3 = (const float*)d_in[7];
    float* out = (float*)d_out;

    char* w = (char*)d_ws;
    float4* At    = (float4*)w; w += SLACK * 16;        // 2.1 MB (sentinel + mask slack)
    float2* xs    = (float2*)w; w += SLACK * 8;         // 1.05 MB
    int*   bh     = (int*)w;    w += NBLK2 * NB * 4;    // 0.9 MB block-hist/offsets
    int*   tot    = (int*)w;    w += NB * 4;
    int*   rsp    = (int*)w;    w += NN * 4;
    float* dinv   = (float*)w;  w += NN * 4;
    int*   binned = (int*)w;    w += NB * CAP * 4;      // 10.8 MB
    int*   csr    = (int*)w;    w += (NB * CAP2 + 16) * 4; // 11.2 MB (+64B overread pad)
    float* h3     = (float*)w;  w += SLACK * 4;         // 0.52 MB

    const int G_N = (NN + 255) / 256;        // 391
    const int G_A = NN / 32;                 // 3125 (exact)

    k_hist<<<NBLK2, 512, 0, stream>>>(ei, bh);
    k_offscan<<<NB, 256, 0, stream>>>(bh, tot);
    k_scatter2<<<NBLK2, 512, 0, stream>>>(ei, bh, binned);
    k_csr_count<<<NB, 256, 0, stream>>>(binned, tot, x, rsp, dinv, xs);
    k_csr_place<<<NB, 256, 0, stream>>>(binned, tot, rsp, xs, dinv, csr, At);
    k_agg<<<G_A, 256, 0, stream>>>(At, rsp, csr, W1, b1, W2, b2, W3, h3);
    k_gather_out<<<G_N, 256, 0, stream>>>(h3, rsp, csr, dinv, b3, out);
}